// Round 2
// baseline (1584.963 us; speedup 1.0000x reference)
//
#include <hip/hip_runtime.h>
#include <math.h>

#define N_NODES 50000
#define N_EDGES 800000
#define HDIM 128
#define EPSV 1e-8f
#define ALPHA 0.3f

// NOTE: harness delivers ALL integer inputs as int32 (q, edge_index, neg_edge_index).
// edge_index layout: flat [2][E] row-major -> ei[0..E) = src, ei[E..2E) = dst.

// ---------------------------------------------------------------------------
// Graph preprocessing
// ---------------------------------------------------------------------------

__global__ __launch_bounds__(256) void k_count(const int* __restrict__ ei,
                                               int* __restrict__ cnt) {
    int e = blockIdx.x * 256 + threadIdx.x;
    if (e < N_EDGES) atomicAdd(&cnt[ei[N_EDGES + e]], 1);
}

__global__ __launch_bounds__(256) void k_invdis(const int* __restrict__ cnt,
                                                float* __restrict__ dis,
                                                float* __restrict__ inv) {
    int i = blockIdx.x * 256 + threadIdx.x;
    if (i < N_NODES) {
        float d = (float)cnt[i] + 1.0f;
        dis[i] = 1.0f / sqrtf(d);
        inv[i] = 1.0f / d;
    }
}

// partial sums of 1024-element chunks
__global__ __launch_bounds__(256) void k_scan_partial(const int* __restrict__ cnt,
                                                      int* __restrict__ partial) {
    int b = blockIdx.x, t = threadIdx.x;
    int base = b * 1024 + t * 4;
    int s = 0;
#pragma unroll
    for (int j = 0; j < 4; ++j) {
        int idx = base + j;
        if (idx < N_NODES) s += cnt[idx];
    }
#pragma unroll
    for (int m = 1; m < 64; m <<= 1) s += __shfl_xor(s, m, 64);
    __shared__ int sh[4];
    if ((t & 63) == 0) sh[t >> 6] = s;
    __syncthreads();
    if (t == 0) partial[b] = sh[0] + sh[1] + sh[2] + sh[3];
}

__global__ void k_scan_mid(int* __restrict__ partial, int* __restrict__ rowptr) {
    int l = threadIdx.x;
    const int NP = (N_NODES + 1023) / 1024;  // 49 <= 64
    int v = (l < NP) ? partial[l] : 0;
    int vin = v;
#pragma unroll
    for (int off = 1; off < 64; off <<= 1) {
        int u = __shfl_up(v, off, 64);
        if (l >= off) v += u;
    }
    if (l < NP) partial[l] = v - vin;          // exclusive
    if (l == NP - 1) rowptr[N_NODES] = v;      // total == E
}

__global__ __launch_bounds__(256) void k_scan_final(const int* __restrict__ cnt,
                                                    const int* __restrict__ partial,
                                                    int* __restrict__ rowptr) {
    int b = blockIdx.x, t = threadIdx.x;
    int base = b * 1024 + t * 4;
    int c[4];
    int s = 0;
#pragma unroll
    for (int j = 0; j < 4; ++j) {
        int idx = base + j;
        c[j] = (idx < N_NODES) ? cnt[idx] : 0;
        s += c[j];
    }
    __shared__ int sh[256];
    sh[t] = s;
    __syncthreads();
    for (int off = 1; off < 256; off <<= 1) {
        int v = 0;
        if (t >= off) v = sh[t - off];
        __syncthreads();
        sh[t] += v;
        __syncthreads();
    }
    int texcl = sh[t] - s;
    int pre = partial[b] + texcl;
#pragma unroll
    for (int j = 0; j < 4; ++j) {
        int idx = base + j;
        if (idx < N_NODES) rowptr[idx] = pre;
        pre += c[j];
    }
}

__global__ __launch_bounds__(256) void k_fill(const int* __restrict__ ei,
                                              const int* __restrict__ rowptr,
                                              int* __restrict__ cursor,
                                              int* __restrict__ col) {
    int e = blockIdx.x * 256 + threadIdx.x;
    if (e < N_EDGES) {
        int d = ei[N_EDGES + e];
        int pos = rowptr[d] + atomicAdd(&cursor[d], 1);
        col[pos] = ei[e];
    }
}

// t = Ahat @ e_q  (one-hot query column of the normalized adjacency)
__global__ __launch_bounds__(256) void k_t(const int* __restrict__ ei,
                                           const int* __restrict__ qp,
                                           const float* __restrict__ dis,
                                           const float* __restrict__ inv,
                                           float* __restrict__ t) {
    int e = blockIdx.x * 256 + threadIdx.x;
    int q = *qp;
    if (e == 0) atomicAdd(&t[q], inv[q]);
    if (e < N_EDGES && ei[e] == q) {
        int d = ei[N_EDGES + e];
        atomicAdd(&t[d], dis[q] * dis[d]);
    }
}

// ---------------------------------------------------------------------------
// Dense GEMM: out[r][c] = sum_k in[r][k] * W[c][k] (+bias +bias2 +add1 +add2, relu)
// K = H = 128 fixed. Tile 64 rows x 128 cols per 256-thread block.
// ---------------------------------------------------------------------------

template <int RELU, int NADD, int HASB2>
__global__ __launch_bounds__(256) void k_gemm(
    const float* __restrict__ in, int ins,
    const float* __restrict__ W,
    const float* __restrict__ bias, const float* __restrict__ bias2,
    const float* __restrict__ add1, int a1s,
    const float* __restrict__ add2, int a2s,
    float* __restrict__ out, int outs, int nrows) {
    __shared__ float inT[64][132];
    __shared__ float Wt[32][128];
    const int tid = threadIdx.x;
    const int row0 = blockIdx.x * 64;

    // stage input tile (64x128)
#pragma unroll
    for (int it = 0; it < 8; ++it) {
        int f = tid + it * 256;
        int r = f >> 5, c4 = (f & 31) * 4;
        int gr = row0 + r;
        float4 v = make_float4(0.f, 0.f, 0.f, 0.f);
        if (gr < nrows) v = *(const float4*)(in + (size_t)gr * ins + c4);
        *(float4*)&inT[r][c4] = v;
    }

    float acc[8][4];
#pragma unroll
    for (int i = 0; i < 8; ++i) acc[i][0] = acc[i][1] = acc[i][2] = acc[i][3] = 0.f;

    const int cg4 = (tid & 31) * 4;
    const int rg = tid >> 5;
    const int wc = tid >> 1, wh = (tid & 1) * 16;

    for (int kk = 0; kk < 128; kk += 32) {
        __syncthreads();
        // stage transposed W chunk: Wt[k][c] = W[c][kk+k]
        const float* wp = W + wc * 128 + kk + wh;
#pragma unroll
        for (int j4 = 0; j4 < 4; ++j4) {
            float4 wv = *(const float4*)(wp + j4 * 4);
            Wt[wh + j4 * 4 + 0][wc] = wv.x;
            Wt[wh + j4 * 4 + 1][wc] = wv.y;
            Wt[wh + j4 * 4 + 2][wc] = wv.z;
            Wt[wh + j4 * 4 + 3][wc] = wv.w;
        }
        __syncthreads();
#pragma unroll
        for (int k = 0; k < 32; ++k) {
            float4 wv = *(const float4*)&Wt[k][cg4];
#pragma unroll
            for (int i = 0; i < 8; ++i) {
                float a = inT[rg + 8 * i][kk + k];
                acc[i][0] = fmaf(a, wv.x, acc[i][0]);
                acc[i][1] = fmaf(a, wv.y, acc[i][1]);
                acc[i][2] = fmaf(a, wv.z, acc[i][2]);
                acc[i][3] = fmaf(a, wv.w, acc[i][3]);
            }
        }
    }

    float4 bv = *(const float4*)(bias + cg4);
    if (HASB2) {
        float4 b2 = *(const float4*)(bias2 + cg4);
        bv.x += b2.x; bv.y += b2.y; bv.z += b2.z; bv.w += b2.w;
    }
#pragma unroll
    for (int i = 0; i < 8; ++i) {
        int r = row0 + rg + 8 * i;
        if (r >= nrows) continue;
        float4 v;
        v.x = acc[i][0] + bv.x;
        v.y = acc[i][1] + bv.y;
        v.z = acc[i][2] + bv.z;
        v.w = acc[i][3] + bv.w;
        if (NADD >= 1) {
            float4 a1 = *(const float4*)(add1 + (size_t)r * a1s + cg4);
            v.x += a1.x; v.y += a1.y; v.z += a1.z; v.w += a1.w;
        }
        if (NADD >= 2) {
            float4 a2 = *(const float4*)(add2 + (size_t)r * a2s + cg4);
            v.x += a2.x; v.y += a2.y; v.z += a2.z; v.w += a2.w;
        }
        if (RELU) {
            v.x = fmaxf(v.x, 0.f); v.y = fmaxf(v.y, 0.f);
            v.z = fmaxf(v.z, 0.f); v.w = fmaxf(v.w, 0.f);
        }
        *(float4*)(out + (size_t)r * outs + cg4) = v;
    }
}

// ---------------------------------------------------------------------------
// SpMM: out[i] = inv[i]*in[i] + dis[i] * sum_{e in row i} dis[src]*in[src]
// One block per node, thread per float2 column pair.
// ---------------------------------------------------------------------------

template <int C>
__global__ void k_spmm(const int* __restrict__ rowptr, const int* __restrict__ col,
                       const float* __restrict__ dis, const float* __restrict__ inv,
                       const float* __restrict__ in, int ins, int inoff,
                       float* __restrict__ out, int outs, int outoff) {
    int i = blockIdx.x;
    int c2 = threadIdx.x * 2;
    int r0 = rowptr[i], r1 = rowptr[i + 1];
    float ax = 0.f, ay = 0.f;
    for (int e = r0; e < r1; ++e) {
        int s = col[e];
        float w = dis[s];
        const float2 v = *(const float2*)(in + (size_t)s * ins + inoff + c2);
        ax = fmaf(w, v.x, ax);
        ay = fmaf(w, v.y, ay);
    }
    const float2 sv = *(const float2*)(in + (size_t)i * ins + inoff + c2);
    float di = dis[i], iv = inv[i];
    float2 o;
    o.x = fmaf(di, ax, iv * sv.x);
    o.y = fmaf(di, ay, iv * sv.y);
    *(float2*)(out + (size_t)i * outs + outoff + c2) = o;
}

// hq0[i][j] = relu(t[i]*wq0[j] + bq0[j])
__global__ __launch_bounds__(256) void k_hq0(const float* __restrict__ t,
                                             const float* __restrict__ wq0,
                                             const float* __restrict__ bq0,
                                             float* __restrict__ B1) {
    int g = blockIdx.x * 256 + threadIdx.x;
    int i = g >> 7, j = g & 127;
    B1[(size_t)i * 384 + j] = fmaxf(fmaf(t[i], wq0[j], bq0[j]), 0.f);
}

// z0[q][:] += w_lq   (rank-1 one-hot part of querys_)
__global__ void k_addwlq(const int* __restrict__ qp, const float* __restrict__ w_lq,
                         float* __restrict__ z0) {
    int j = threadIdx.x;
    int q = *qp;
    z0[(size_t)q * 384 + j] += w_lq[j];
}

// ---------------------------------------------------------------------------
// Decode
// ---------------------------------------------------------------------------

__global__ void k_qemb(const int* __restrict__ qp, const float* __restrict__ x,
                       float* __restrict__ qe) {
    int j = threadIdx.x;  // 128 threads
    int q = *qp;
    float v = x[(size_t)q * 384 + j];
    qe[j] = v;
    float s = v * v;
#pragma unroll
    for (int m = 1; m < 64; m <<= 1) s += __shfl_xor(s, m, 64);
    __shared__ float sh[2];
    if ((j & 63) == 0) sh[j >> 6] = s;
    __syncthreads();
    if (j == 0) qe[128] = fmaxf(sqrtf(sh[0] + sh[1]), EPSV);
}

__global__ __launch_bounds__(256) void k_node(const float* __restrict__ x,
                                              const float* __restrict__ qe,
                                              const float* __restrict__ m2w1,
                                              const float* __restrict__ m2b1,
                                              const float* __restrict__ m2w2,
                                              const float* __restrict__ m2b2,
                                              float* __restrict__ out) {
    int node = blockIdx.x * 4 + (threadIdx.x >> 6);
    int lane = threadIdx.x & 63;
    const float2 xv = *(const float2*)(x + (size_t)node * 384 + 2 * lane);
    const float2 qv = *(const float2*)(qe + 2 * lane);
    const float2 wv = *(const float2*)(m2w1 + 2 * lane);
    float dq = xv.x * qv.x + xv.y * qv.y;
    float dx = xv.x * xv.x + xv.y * xv.y;
    float dw = xv.x * wv.x + xv.y * wv.y;
#pragma unroll
    for (int m = 1; m < 64; m <<= 1) {
        dq += __shfl_xor(dq, m, 64);
        dx += __shfl_xor(dx, m, 64);
        dw += __shfl_xor(dw, m, 64);
    }
    if (lane == 0) {
        float qn = qe[128];
        float vn = fmaxf(sqrtf(dx), EPSV);
        float simq = dq / (vn * qn);
        float l1 = dw + m2b1[0];
        float s2 = fmaxf(l1, 0.f) * m2w2[0] + m2b2[0];
        float sim = ((1.f - ALPHA) * simq + ALPHA * s2) * 2.f;
        out[node] = 1.f / (1.f + expf(-sim));
    }
}

template <int NEG>
__global__ __launch_bounds__(256) void k_edge(const int* __restrict__ ei,
                                              const float* __restrict__ x,
                                              const float* __restrict__ qe,
                                              float* __restrict__ lossout) {
    int g = threadIdx.x >> 6, lane = threadIdx.x & 63;
    float qn = qe[128];
    const float2 qv = *(const float2*)(qe + 2 * lane);
    float local = 0.f;
    for (int e = blockIdx.x * 4 + g; e < N_EDGES; e += gridDim.x * 4) {
        int s = ei[e], d = ei[N_EDGES + e];
        float2 a = *(const float2*)(x + (size_t)s * 384 + 2 * lane);
        float2 b = *(const float2*)(x + (size_t)d * 384 + 2 * lane);
        float vx = 0.5f * (a.x + b.x), vy = 0.5f * (a.y + b.y);
        float dq = vx * qv.x + vy * qv.y;
        float dv = vx * vx + vy * vy;
#pragma unroll
        for (int m = 1; m < 64; m <<= 1) {
            dq += __shfl_xor(dq, m, 64);
            dv += __shfl_xor(dv, m, 64);
        }
        if (lane == 0) {
            float vn = fmaxf(sqrtf(dv), EPSV);
            float cs = dq / (vn * qn);
            float sgn = NEG ? cs : -cs;
            local += log1pf(expf(sgn));
        }
    }
    __shared__ float sh[4];
    if (lane == 0) sh[g] = local;
    __syncthreads();
    if (threadIdx.x == 0) {
        float tot = (sh[0] + sh[1] + sh[2] + sh[3]) * (1.0f / N_EDGES);
        atomicAdd(lossout, tot);
    }
}

// ---------------------------------------------------------------------------
// Launch
// ---------------------------------------------------------------------------

extern "C" void kernel_launch(void* const* d_in, const int* in_sizes, int n_in,
                              void* d_out, int out_size, void* d_ws, size_t ws_size,
                              hipStream_t stream) {
    const int* qp = (const int*)d_in[0];
    const float* feats = (const float*)d_in[1];
    const int* ei = (const int*)d_in[2];
    const int* nei = (const int*)d_in[3];
    const float *w_lq = (const float*)d_in[4], *b_lq = (const float*)d_in[5];
    const float *w_lf = (const float*)d_in[6], *b_lf = (const float*)d_in[7];
    const float *wq0 = (const float*)d_in[8], *bq0 = (const float*)d_in[9];
    const float *wq1 = (const float*)d_in[10], *bq1 = (const float*)d_in[11];
    const float *wq2 = (const float*)d_in[12], *bq2 = (const float*)d_in[13];
    const float *wx0 = (const float*)d_in[14], *bx0 = (const float*)d_in[15];
    const float *wx1 = (const float*)d_in[16], *bx1 = (const float*)d_in[17];
    const float *wx2 = (const float*)d_in[18], *bx2 = (const float*)d_in[19];
    const float *wf0 = (const float*)d_in[20], *bf0 = (const float*)d_in[21];
    const float *wf1 = (const float*)d_in[22], *bf1 = (const float*)d_in[23];
    const float *wf2 = (const float*)d_in[24], *bf2 = (const float*)d_in[25];
    const float *m1w1 = (const float*)d_in[26], *m1b1 = (const float*)d_in[27];
    const float *m1w2 = (const float*)d_in[28], *m1b2 = (const float*)d_in[29];
    const float *m2w1 = (const float*)d_in[30], *m2b1 = (const float*)d_in[31];
    const float *m2w2 = (const float*)d_in[32], *m2b2 = (const float*)d_in[33];
    float* out = (float*)d_out;

    // workspace bump allocator (~158 MiB total)
    char* p = (char*)d_ws;
    auto alloc = [&](size_t b) -> char* {
        char* r = p;
        p += (b + 255) & ~(size_t)255;
        return r;
    };
    float* dis = (float*)alloc(N_NODES * 4);
    float* inv = (float*)alloc(N_NODES * 4);
    float* t = (float*)alloc(N_NODES * 4);
    float* qe = (float*)alloc(129 * 4);
    int* cnt = (int*)alloc(N_NODES * 4);
    int* cursor = (int*)alloc(N_NODES * 4);
    int* rowptr = (int*)alloc((N_NODES + 1) * 4);
    int* partial = (int*)alloc(64 * 4);
    int* col = (int*)alloc(N_EDGES * 4);
    float* B1 = (float*)alloc((size_t)N_NODES * 384 * 4);  // [hq|h|hf] stacked
    float* B2 = (float*)alloc((size_t)N_NODES * 384 * 4);  // aggregation outputs

    const int EB = (N_EDGES + 255) / 256;
    const int NB = (N_NODES + 255) / 256;
    const int NP = (N_NODES + 1023) / 1024;
    const int GB = (N_NODES + 63) / 64;

    hipMemsetAsync(cnt, 0, N_NODES * 4, stream);
    hipMemsetAsync(cursor, 0, N_NODES * 4, stream);
    hipMemsetAsync(t, 0, N_NODES * 4, stream);
    hipMemsetAsync(out + N_NODES, 0, 4, stream);

    // preprocessing: degrees, CSR (sorted-by-dst), t vector
    k_count<<<EB, 256, 0, stream>>>(ei, cnt);
    k_invdis<<<NB, 256, 0, stream>>>(cnt, dis, inv);
    k_scan_partial<<<NP, 256, 0, stream>>>(cnt, partial);
    k_scan_mid<<<1, 64, 0, stream>>>(partial, rowptr);
    k_scan_final<<<NP, 256, 0, stream>>>(cnt, partial, rowptr);
    k_fill<<<EB, 256, 0, stream>>>(ei, rowptr, cursor, col);
    k_t<<<EB, 256, 0, stream>>>(ei, qp, dis, inv, t);

    // z0 = querys_ + feats_ = feats@w_lf.T + b_lf + b_lq (+ w_lq at row q)
    k_gemm<0, 0, 1><<<GB, 256, 0, stream>>>(feats, 128, w_lf, b_lf, b_lq,
                                            nullptr, 0, nullptr, 0, B1 + 256, 384, N_NODES);
    k_addwlq<<<1, 128, 0, stream>>>(qp, w_lq, B1 + 256);

    // layer 0 aggregations: Ahat@feats -> B2.h ; Ahat@z0 -> B2.hf
    k_spmm<128><<<N_NODES, 64, 0, stream>>>(rowptr, col, dis, inv, feats, 128, 0, B2, 384, 128);
    k_spmm<128><<<N_NODES, 64, 0, stream>>>(rowptr, col, dis, inv, B1, 384, 256, B2, 384, 256);
    k_hq0<<<(N_NODES * 128) / 256, 256, 0, stream>>>(t, wq0, bq0, B1);
    k_gemm<1, 0, 0><<<GB, 256, 0, stream>>>(B2 + 128, 384, wx0, bx0, nullptr,
                                            nullptr, 0, nullptr, 0, B1 + 128, 384, N_NODES);
    k_gemm<1, 2, 0><<<GB, 256, 0, stream>>>(B2 + 256, 384, wf0, bf0, nullptr,
                                            B1 + 0, 384, B1 + 128, 384, B1 + 256, 384, N_NODES);

    // layer 1
    k_spmm<384><<<N_NODES, 192, 0, stream>>>(rowptr, col, dis, inv, B1, 384, 0, B2, 384, 0);
    k_gemm<1, 0, 0><<<GB, 256, 0, stream>>>(B2 + 0, 384, wq1, bq1, nullptr,
                                            nullptr, 0, nullptr, 0, B1 + 0, 384, N_NODES);
    k_gemm<1, 0, 0><<<GB, 256, 0, stream>>>(B2 + 128, 384, wx1, bx1, nullptr,
                                            nullptr, 0, nullptr, 0, B1 + 128, 384, N_NODES);
    k_gemm<1, 2, 0><<<GB, 256, 0, stream>>>(B2 + 256, 384, wf1, bf1, nullptr,
                                            B1 + 0, 384, B1 + 128, 384, B1 + 256, 384, N_NODES);

    // layer 2 (no relu)
    k_spmm<384><<<N_NODES, 192, 0, stream>>>(rowptr, col, dis, inv, B1, 384, 0, B2, 384, 0);
    k_gemm<0, 0, 0><<<GB, 256, 0, stream>>>(B2 + 0, 384, wq2, bq2, nullptr,
                                            nullptr, 0, nullptr, 0, B1 + 0, 384, N_NODES);
    k_gemm<0, 0, 0><<<GB, 256, 0, stream>>>(B2 + 128, 384, wx2, bx2, nullptr,
                                            nullptr, 0, nullptr, 0, B1 + 128, 384, N_NODES);
    k_gemm<0, 2, 0><<<GB, 256, 0, stream>>>(B2 + 256, 384, wf2, bf2, nullptr,
                                            B1 + 0, 384, B1 + 128, 384, B1 + 256, 384, N_NODES);

    // mlp1: y = relu(hf@m1w1.T+b) -> B2.hq ; x = y@m1w2.T+b -> B1.hq (stride 384)
    k_gemm<1, 0, 0><<<GB, 256, 0, stream>>>(B1 + 256, 384, m1w1, m1b1, nullptr,
                                            nullptr, 0, nullptr, 0, B2 + 0, 384, N_NODES);
    k_gemm<0, 0, 0><<<GB, 256, 0, stream>>>(B2 + 0, 384, m1w2, m1b2, nullptr,
                                            nullptr, 0, nullptr, 0, B1 + 0, 384, N_NODES);

    // decode
    k_qemb<<<1, 128, 0, stream>>>(qp, B1, qe);
    k_node<<<N_NODES / 4, 256, 0, stream>>>(B1, qe, m2w1, m2b1, m2w2, m2b2, out);
    k_edge<0><<<1024, 256, 0, stream>>>(ei, B1, qe, out + N_NODES);
    k_edge<1><<<1024, 256, 0, stream>>>(nei, B1, qe, out + N_NODES);
}

// Round 3
// 734.263 us; speedup vs baseline: 2.1586x; 2.1586x over previous
//
#include <hip/hip_runtime.h>
#include <math.h>

#define N_NODES 50000
#define N_EDGES 800000
#define EPSV 1e-8f
#define ALPHA 0.3f

typedef __attribute__((ext_vector_type(8))) unsigned short ushort8;
typedef __attribute__((ext_vector_type(8))) short short8;
typedef __attribute__((ext_vector_type(4))) float floatx4;

__device__ inline float b2f(unsigned short u) {
    union { unsigned i; float f; } c; c.i = ((unsigned)u) << 16; return c.f;
}
__device__ inline unsigned short f2b(float f) {
    union { float f; unsigned i; } c; c.f = f;
    return (unsigned short)((c.i + 0x7FFFu + ((c.i >> 16) & 1u)) >> 16);
}

// ---------------------------------------------------------------------------
// Graph preprocessing (unchanged from round 2)
// ---------------------------------------------------------------------------

__global__ __launch_bounds__(256) void k_count(const int* __restrict__ ei,
                                               int* __restrict__ cnt) {
    int e = blockIdx.x * 256 + threadIdx.x;
    if (e < N_EDGES) atomicAdd(&cnt[ei[N_EDGES + e]], 1);
}

__global__ __launch_bounds__(256) void k_invdis(const int* __restrict__ cnt,
                                                float* __restrict__ dis,
                                                float* __restrict__ inv) {
    int i = blockIdx.x * 256 + threadIdx.x;
    if (i < N_NODES) {
        float d = (float)cnt[i] + 1.0f;
        dis[i] = 1.0f / sqrtf(d);
        inv[i] = 1.0f / d;
    }
}

__global__ __launch_bounds__(256) void k_scan_partial(const int* __restrict__ cnt,
                                                      int* __restrict__ partial) {
    int b = blockIdx.x, t = threadIdx.x;
    int base = b * 1024 + t * 4;
    int s = 0;
#pragma unroll
    for (int j = 0; j < 4; ++j) {
        int idx = base + j;
        if (idx < N_NODES) s += cnt[idx];
    }
#pragma unroll
    for (int m = 1; m < 64; m <<= 1) s += __shfl_xor(s, m, 64);
    __shared__ int sh[4];
    if ((t & 63) == 0) sh[t >> 6] = s;
    __syncthreads();
    if (t == 0) partial[b] = sh[0] + sh[1] + sh[2] + sh[3];
}

__global__ void k_scan_mid(int* __restrict__ partial, int* __restrict__ rowptr) {
    int l = threadIdx.x;
    const int NP = (N_NODES + 1023) / 1024;
    int v = (l < NP) ? partial[l] : 0;
    int vin = v;
#pragma unroll
    for (int off = 1; off < 64; off <<= 1) {
        int u = __shfl_up(v, off, 64);
        if (l >= off) v += u;
    }
    if (l < NP) partial[l] = v - vin;
    if (l == NP - 1) rowptr[N_NODES] = v;
}

__global__ __launch_bounds__(256) void k_scan_final(const int* __restrict__ cnt,
                                                    const int* __restrict__ partial,
                                                    int* __restrict__ rowptr) {
    int b = blockIdx.x, t = threadIdx.x;
    int base = b * 1024 + t * 4;
    int c[4];
    int s = 0;
#pragma unroll
    for (int j = 0; j < 4; ++j) {
        int idx = base + j;
        c[j] = (idx < N_NODES) ? cnt[idx] : 0;
        s += c[j];
    }
    __shared__ int sh[256];
    sh[t] = s;
    __syncthreads();
    for (int off = 1; off < 256; off <<= 1) {
        int v = 0;
        if (t >= off) v = sh[t - off];
        __syncthreads();
        sh[t] += v;
        __syncthreads();
    }
    int texcl = sh[t] - s;
    int pre = partial[b] + texcl;
#pragma unroll
    for (int j = 0; j < 4; ++j) {
        int idx = base + j;
        if (idx < N_NODES) rowptr[idx] = pre;
        pre += c[j];
    }
}

__global__ __launch_bounds__(256) void k_fill(const int* __restrict__ ei,
                                              const int* __restrict__ rowptr,
                                              int* __restrict__ cursor,
                                              int* __restrict__ col) {
    int e = blockIdx.x * 256 + threadIdx.x;
    if (e < N_EDGES) {
        int d = ei[N_EDGES + e];
        int pos = rowptr[d] + atomicAdd(&cursor[d], 1);
        col[pos] = ei[e];
    }
}

__global__ __launch_bounds__(256) void k_t(const int* __restrict__ ei,
                                           const int* __restrict__ qp,
                                           const float* __restrict__ dis,
                                           const float* __restrict__ inv,
                                           float* __restrict__ t) {
    int e = blockIdx.x * 256 + threadIdx.x;
    int q = *qp;
    if (e == 0) atomicAdd(&t[q], inv[q]);
    if (e < N_EDGES && ei[e] == q) {
        int d = ei[N_EDGES + e];
        atomicAdd(&t[d], dis[q] * dis[d]);
    }
}

// feats (fp32) -> bf16 copy
__global__ __launch_bounds__(256) void k_cast(const float* __restrict__ in,
                                              unsigned short* __restrict__ out, int n8) {
    int id = blockIdx.x * 256 + threadIdx.x;
    if (id >= n8) return;
    const float4 a = *(const float4*)(in + id * 8);
    const float4 b = *(const float4*)(in + id * 8 + 4);
    ushort8 o;
    o[0] = f2b(a.x); o[1] = f2b(a.y); o[2] = f2b(a.z); o[3] = f2b(a.w);
    o[4] = f2b(b.x); o[5] = f2b(b.y); o[6] = f2b(b.z); o[7] = f2b(b.w);
    *(ushort8*)(out + id * 8) = o;
}

// ---------------------------------------------------------------------------
// MFMA bf16 GEMM: out[r][c] = sum_k A[r][k]*W[c][k] (+bias(+bias2) +adds, relu)
// M tile 128, N=K=128 full. A bf16 in global; W fp32 cast to bf16 in LDS.
// Both LDS tiles XOR-swizzled: byte ^= ((row&7)<<4)  (T2, 16->2-way conflicts)
// ---------------------------------------------------------------------------

template <int RELU, int NADD, int HASB2, int WF32>
__global__ __launch_bounds__(256) void k_gemm(
    const unsigned short* __restrict__ A, int As,
    const float* __restrict__ W,
    const float* __restrict__ bias, const float* __restrict__ bias2,
    const unsigned short* __restrict__ add1, int a1s,
    const unsigned short* __restrict__ add2, int a2s,
    unsigned short* __restrict__ outh, int ohs,
    float* __restrict__ outf, int ofs, int nrows) {
    __shared__ unsigned short Al[128 * 128];
    __shared__ unsigned short Wl[128 * 128];
    const int tid = threadIdx.x;
    const int row0 = blockIdx.x * 128;
    const int t4 = tid >> 4, c16 = tid & 15;

    // stage A (bf16, swizzled): 8 issues x 256 threads x 16B
#pragma unroll
    for (int it = 0; it < 8; ++it) {
        int r = it * 16 + t4;
        int gr = row0 + r; if (gr > nrows - 1) gr = nrows - 1;  // clamp: tail rows unused
        ushort8 v = *(const ushort8*)(A + (size_t)gr * As + c16 * 8);
        int boff = (c16 * 16) ^ ((r & 7) << 4);
        *(ushort8*)((char*)Al + r * 256 + boff) = v;
    }
    // stage W (fp32 -> bf16, swizzled)
#pragma unroll
    for (int it = 0; it < 8; ++it) {
        int c = it * 16 + t4;
        const float* wp = W + c * 128 + c16 * 8;
        float4 w0 = *(const float4*)wp;
        float4 w1 = *(const float4*)(wp + 4);
        ushort8 v;
        v[0] = f2b(w0.x); v[1] = f2b(w0.y); v[2] = f2b(w0.z); v[3] = f2b(w0.w);
        v[4] = f2b(w1.x); v[5] = f2b(w1.y); v[6] = f2b(w1.z); v[7] = f2b(w1.w);
        int boff = (c16 * 16) ^ ((c & 7) << 4);
        *(ushort8*)((char*)Wl + c * 256 + boff) = v;
    }
    __syncthreads();

    const int wv = tid >> 6, l = tid & 63;
    const int lr = l & 15, lg = l >> 4;
    const int sx = (lr & 7) << 4;  // row&7 == lr&7 for all tiles (tile strides are mult of 8)

    floatx4 acc[8][2];
#pragma unroll
    for (int i = 0; i < 8; ++i)
#pragma unroll
        for (int j = 0; j < 2; ++j) acc[i][j] = (floatx4){0.f, 0.f, 0.f, 0.f};

#pragma unroll
    for (int ks = 0; ks < 4; ++ks) {
        int ko = (ks * 64 + lg * 16) ^ sx;
        short8 bfr[2];
#pragma unroll
        for (int ct = 0; ct < 2; ++ct) {
            int c = wv * 32 + ct * 16 + lr;
            bfr[ct] = *(const short8*)((char*)Wl + c * 256 + ko);
        }
#pragma unroll
        for (int rt = 0; rt < 8; ++rt) {
            int r = rt * 16 + lr;
            short8 af = *(const short8*)((char*)Al + r * 256 + ko);
            acc[rt][0] = __builtin_amdgcn_mfma_f32_16x16x32_bf16(af, bfr[0], acc[rt][0], 0, 0, 0);
            acc[rt][1] = __builtin_amdgcn_mfma_f32_16x16x32_bf16(af, bfr[1], acc[rt][1], 0, 0, 0);
        }
    }

    // epilogue: C/D layout col=lane&15, row=(lane>>4)*4+reg
#pragma unroll
    for (int ct = 0; ct < 2; ++ct) {
        int colc = wv * 32 + ct * 16 + lr;
        float bv = bias[colc];
        if (HASB2) bv += bias2[colc];
#pragma unroll
        for (int rt = 0; rt < 8; ++rt) {
            int rbase = row0 + rt * 16 + lg * 4;
#pragma unroll
            for (int reg = 0; reg < 4; ++reg) {
                int r = rbase + reg;
                if (r >= nrows) continue;
                float v = acc[rt][ct][reg] + bv;
                if (NADD >= 1) v += b2f(add1[(size_t)r * a1s + colc]);
                if (NADD >= 2) v += b2f(add2[(size_t)r * a2s + colc]);
                if (RELU) v = fmaxf(v, 0.f);
                outh[(size_t)r * ohs + colc] = f2b(v);
                if (WF32) outf[(size_t)r * ofs + colc] = v;
            }
        }
    }
}

// ---------------------------------------------------------------------------
// SpMM (bf16 in/out, fp32 accum): out[i] = dis_i * sum_e dis_s*in[s] + inv_i*in[i]
// 1 wave per (node, 128-col block); 4 edges in parallel via 16-lane groups.
// ---------------------------------------------------------------------------

__global__ void k_agg(const int* __restrict__ rowptr, const int* __restrict__ col,
                      const float* __restrict__ dis, const float* __restrict__ inv,
                      const unsigned short* __restrict__ in, int ins, int incb,
                      unsigned short* __restrict__ out, int outs, int outcb) {
    int i = blockIdx.x;
    int cb = blockIdx.y * 128;
    int l = threadIdx.x;
    int g = l >> 4, li = l & 15;
    int r0 = rowptr[i], r1 = rowptr[i + 1];
    float acc[8] = {0.f, 0.f, 0.f, 0.f, 0.f, 0.f, 0.f, 0.f};
    for (int base = r0; base < r1; base += 4) {
        int e = base + g;
        float w = 0.f;
        int s = i;
        if (e < r1) { s = col[e]; w = dis[s]; }
        ushort8 v = *(const ushort8*)(in + (size_t)s * ins + incb + cb + li * 8);
#pragma unroll
        for (int j = 0; j < 8; ++j) acc[j] = fmaf(w, b2f(v[j]), acc[j]);
    }
#pragma unroll
    for (int j = 0; j < 8; ++j) {
        acc[j] += __shfl_xor(acc[j], 16, 64);
        acc[j] += __shfl_xor(acc[j], 32, 64);
    }
    if (g == 0) {
        ushort8 sv = *(const ushort8*)(in + (size_t)i * ins + incb + cb + li * 8);
        float di = dis[i], iv = inv[i];
        ushort8 o;
#pragma unroll
        for (int j = 0; j < 8; ++j) o[j] = f2b(fmaf(di, acc[j], iv * b2f(sv[j])));
        *(ushort8*)(out + (size_t)i * outs + outcb + cb + li * 8) = o;
    }
}

// hq0[i][j] = relu(t[i]*wq0[j] + bq0[j])  (bf16 out)
__global__ __launch_bounds__(256) void k_hq0(const float* __restrict__ t,
                                             const float* __restrict__ wq0,
                                             const float* __restrict__ bq0,
                                             unsigned short* __restrict__ B1h) {
    int gidx = blockIdx.x * 256 + threadIdx.x;
    int i = gidx >> 7, j = gidx & 127;
    B1h[(size_t)i * 384 + j] = f2b(fmaxf(fmaf(t[i], wq0[j], bq0[j]), 0.f));
}

// z0h[q][:] += w_lq (rank-1 one-hot part of querys_)
__global__ void k_addwlq(const int* __restrict__ qp, const float* __restrict__ w_lq,
                         unsigned short* __restrict__ z0h) {
    int j = threadIdx.x;
    int q = *qp;
    z0h[(size_t)q * 128 + j] = f2b(b2f(z0h[(size_t)q * 128 + j]) + w_lq[j]);
}

// ---------------------------------------------------------------------------
// Decode
// ---------------------------------------------------------------------------

__global__ void k_qemb(const int* __restrict__ qp, const float* __restrict__ xf,
                       float* __restrict__ qe) {
    int j = threadIdx.x;  // 128
    int q = *qp;
    float v = xf[(size_t)q * 128 + j];
    qe[j] = v;
    float s = v * v;
#pragma unroll
    for (int m = 1; m < 64; m <<= 1) s += __shfl_xor(s, m, 64);
    __shared__ float sh[2];
    if ((j & 63) == 0) sh[j >> 6] = s;
    __syncthreads();
    if (j == 0) qe[128] = fmaxf(sqrtf(sh[0] + sh[1]), EPSV);
}

// per-node: sigmoid output + a[i]=x.q, n2[i]=|x|^2 (all fp32)
__global__ __launch_bounds__(256) void k_node(const float* __restrict__ xf,
                                              const float* __restrict__ qe,
                                              const float* __restrict__ m2w1,
                                              const float* __restrict__ m2b1,
                                              const float* __restrict__ m2w2,
                                              const float* __restrict__ m2b2,
                                              float* __restrict__ out,
                                              float* __restrict__ a,
                                              float* __restrict__ n2) {
    int node = blockIdx.x * 4 + (threadIdx.x >> 6);
    int lane = threadIdx.x & 63;
    const float2 xv = *(const float2*)(xf + (size_t)node * 128 + 2 * lane);
    const float2 qv = *(const float2*)(qe + 2 * lane);
    const float2 wv = *(const float2*)(m2w1 + 2 * lane);
    float dq = xv.x * qv.x + xv.y * qv.y;
    float dx = xv.x * xv.x + xv.y * xv.y;
    float dw = xv.x * wv.x + xv.y * wv.y;
#pragma unroll
    for (int m = 1; m < 64; m <<= 1) {
        dq += __shfl_xor(dq, m, 64);
        dx += __shfl_xor(dx, m, 64);
        dw += __shfl_xor(dw, m, 64);
    }
    if (lane == 0) {
        float qn = qe[128];
        float vn = fmaxf(sqrtf(dx), EPSV);
        float simq = dq / (vn * qn);
        float l1 = dw + m2b1[0];
        float s2 = fmaxf(l1, 0.f) * m2w2[0] + m2b2[0];
        float sim = ((1.f - ALPHA) * simq + ALPHA * s2) * 2.f;
        out[node] = 1.f / (1.f + expf(-sim));
        a[node] = dq;
        n2[node] = dx;
    }
}

// fused pos+neg edge BCE loss; 16 lanes per edge; dot from bf16 x-table
__global__ __launch_bounds__(256) void k_loss(const int* __restrict__ ei,
                                              const int* __restrict__ nei,
                                              const unsigned short* __restrict__ xh,
                                              const float* __restrict__ a,
                                              const float* __restrict__ n2,
                                              const float* __restrict__ qe,
                                              float* __restrict__ lossout) {
    int l = threadIdx.x & 63, wvi = threadIdx.x >> 6;
    int g = l >> 4, li = l & 15;
    float qn = qe[128];
    float local = 0.f;
    const int tot = 2 * N_EDGES;
    const int stride = gridDim.x * 16;
    for (int e = blockIdx.x * 16 + wvi * 4 + g; e < tot; e += stride) {
        const int* Ep = (e < N_EDGES) ? ei : nei;
        int eo = (e < N_EDGES) ? e : e - N_EDGES;
        int s = Ep[eo], d = Ep[eo + N_EDGES];
        ushort8 va = *(const ushort8*)(xh + (size_t)s * 128 + li * 8);
        ushort8 vb = *(const ushort8*)(xh + (size_t)d * 128 + li * 8);
        float dsd = 0.f;
#pragma unroll
        for (int j = 0; j < 8; ++j) dsd = fmaf(b2f(va[j]), b2f(vb[j]), dsd);
        dsd += __shfl_xor(dsd, 1, 64);
        dsd += __shfl_xor(dsd, 2, 64);
        dsd += __shfl_xor(dsd, 4, 64);
        dsd += __shfl_xor(dsd, 8, 64);
        if (li == 0) {
            float nv = 0.25f * (n2[s] + n2[d] + 2.f * dsd);
            float vn = fmaxf(sqrtf(fmaxf(nv, 0.f)), EPSV);
            float num = 0.5f * (a[s] + a[d]);
            float cs = num / (vn * qn);
            float sg = (e < N_EDGES) ? -cs : cs;
            local += log1pf(expf(sg));
        }
    }
    local += __shfl_xor(local, 16, 64);
    local += __shfl_xor(local, 32, 64);
    __shared__ float sh[4];
    if (l == 0) sh[wvi] = local;
    __syncthreads();
    if (threadIdx.x == 0)
        atomicAdd(lossout, (sh[0] + sh[1] + sh[2] + sh[3]) * (1.f / N_EDGES));
}

// ---------------------------------------------------------------------------
// Launch
// ---------------------------------------------------------------------------

extern "C" void kernel_launch(void* const* d_in, const int* in_sizes, int n_in,
                              void* d_out, int out_size, void* d_ws, size_t ws_size,
                              hipStream_t stream) {
    const int* qp = (const int*)d_in[0];
    const float* feats = (const float*)d_in[1];
    const int* ei = (const int*)d_in[2];
    const int* nei = (const int*)d_in[3];
    const float *w_lq = (const float*)d_in[4], *b_lq = (const float*)d_in[5];
    const float *w_lf = (const float*)d_in[6], *b_lf = (const float*)d_in[7];
    const float *wq0 = (const float*)d_in[8], *bq0 = (const float*)d_in[9];
    const float *wq1 = (const float*)d_in[10], *bq1 = (const float*)d_in[11];
    const float *wq2 = (const float*)d_in[12], *bq2 = (const float*)d_in[13];
    const float *wx0 = (const float*)d_in[14], *bx0 = (const float*)d_in[15];
    const float *wx1 = (const float*)d_in[16], *bx1 = (const float*)d_in[17];
    const float *wx2 = (const float*)d_in[18], *bx2 = (const float*)d_in[19];
    const float *wf0 = (const float*)d_in[20], *bf0 = (const float*)d_in[21];
    const float *wf1 = (const float*)d_in[22], *bf1 = (const float*)d_in[23];
    const float *wf2 = (const float*)d_in[24], *bf2 = (const float*)d_in[25];
    const float *m1w1 = (const float*)d_in[26], *m1b1 = (const float*)d_in[27];
    const float *m1w2 = (const float*)d_in[28], *m1b2 = (const float*)d_in[29];
    const float *m2w1 = (const float*)d_in[30], *m2b1 = (const float*)d_in[31];
    const float *m2w2 = (const float*)d_in[32], *m2b2 = (const float*)d_in[33];
    float* out = (float*)d_out;

    char* p = (char*)d_ws;
    auto alloc = [&](size_t b) -> char* {
        char* r = p;
        p += (b + 255) & ~(size_t)255;
        return r;
    };
    float* dis = (float*)alloc(N_NODES * 4);
    float* inv = (float*)alloc(N_NODES * 4);
    float* t = (float*)alloc(N_NODES * 4);
    float* qe = (float*)alloc(129 * 4);
    float* a = (float*)alloc(N_NODES * 4);
    float* n2 = (float*)alloc(N_NODES * 4);
    int* cnt = (int*)alloc(N_NODES * 4);
    int* cursor = (int*)alloc(N_NODES * 4);
    int* rowptr = (int*)alloc((N_NODES + 1) * 4);
    int* partial = (int*)alloc(64 * 4);
    int* col = (int*)alloc(N_EDGES * 4);
    unsigned short* featsh = (unsigned short*)alloc((size_t)N_NODES * 128 * 2);
    unsigned short* z0h = (unsigned short*)alloc((size_t)N_NODES * 128 * 2);
    unsigned short* B1h = (unsigned short*)alloc((size_t)N_NODES * 384 * 2);
    unsigned short* B2h = (unsigned short*)alloc((size_t)N_NODES * 384 * 2);
    unsigned short* xh = (unsigned short*)alloc((size_t)N_NODES * 128 * 2);
    float* xf = (float*)alloc((size_t)N_NODES * 128 * 4);

    const int EB = (N_EDGES + 255) / 256;
    const int NB = (N_NODES + 255) / 256;
    const int NP = (N_NODES + 1023) / 1024;
    const int GB = (N_NODES + 127) / 128;  // 391 GEMM blocks

    hipMemsetAsync(cnt, 0, N_NODES * 4, stream);
    hipMemsetAsync(cursor, 0, N_NODES * 4, stream);
    hipMemsetAsync(t, 0, N_NODES * 4, stream);
    hipMemsetAsync(out + N_NODES, 0, 4, stream);

    // preprocessing
    k_count<<<EB, 256, 0, stream>>>(ei, cnt);
    k_invdis<<<NB, 256, 0, stream>>>(cnt, dis, inv);
    k_scan_partial<<<NP, 256, 0, stream>>>(cnt, partial);
    k_scan_mid<<<1, 64, 0, stream>>>(partial, rowptr);
    k_scan_final<<<NP, 256, 0, stream>>>(cnt, partial, rowptr);
    k_fill<<<EB, 256, 0, stream>>>(ei, rowptr, cursor, col);
    k_t<<<EB, 256, 0, stream>>>(ei, qp, dis, inv, t);
    k_cast<<<(N_NODES * 128 / 8 + 255) / 256, 256, 0, stream>>>(feats, featsh,
                                                                N_NODES * 128 / 8);

    // z0 = feats@w_lf.T + b_lf + b_lq (+ w_lq at row q)  -> z0h bf16
    k_gemm<0, 0, 1, 0><<<GB, 256, 0, stream>>>(featsh, 128, w_lf, b_lf, b_lq,
                                               nullptr, 0, nullptr, 0,
                                               z0h, 128, nullptr, 0, N_NODES);
    k_addwlq<<<1, 128, 0, stream>>>(qp, w_lq, z0h);

    // layer 0
    k_hq0<<<(N_NODES * 128) / 256, 256, 0, stream>>>(t, wq0, bq0, B1h);
    k_agg<<<dim3(N_NODES, 1), 64, 0, stream>>>(rowptr, col, dis, inv, featsh, 128, 0,
                                               B2h, 384, 128);
    k_agg<<<dim3(N_NODES, 1), 64, 0, stream>>>(rowptr, col, dis, inv, z0h, 128, 0,
                                               B2h, 384, 256);
    k_gemm<1, 0, 0, 0><<<GB, 256, 0, stream>>>(B2h + 128, 384, wx0, bx0, nullptr,
                                               nullptr, 0, nullptr, 0,
                                               B1h + 128, 384, nullptr, 0, N_NODES);
    k_gemm<1, 2, 0, 0><<<GB, 256, 0, stream>>>(B2h + 256, 384, wf0, bf0, nullptr,
                                               B1h + 0, 384, B1h + 128, 384,
                                               B1h + 256, 384, nullptr, 0, N_NODES);

    // layer 1
    k_agg<<<dim3(N_NODES, 3), 64, 0, stream>>>(rowptr, col, dis, inv, B1h, 384, 0,
                                               B2h, 384, 0);
    k_gemm<1, 0, 0, 0><<<GB, 256, 0, stream>>>(B2h + 0, 384, wq1, bq1, nullptr,
                                               nullptr, 0, nullptr, 0,
                                               B1h + 0, 384, nullptr, 0, N_NODES);
    k_gemm<1, 0, 0, 0><<<GB, 256, 0, stream>>>(B2h + 128, 384, wx1, bx1, nullptr,
                                               nullptr, 0, nullptr, 0,
                                               B1h + 128, 384, nullptr, 0, N_NODES);
    k_gemm<1, 2, 0, 0><<<GB, 256, 0, stream>>>(B2h + 256, 384, wf1, bf1, nullptr,
                                               B1h + 0, 384, B1h + 128, 384,
                                               B1h + 256, 384, nullptr, 0, N_NODES);

    // layer 2 (no relu)
    k_agg<<<dim3(N_NODES, 3), 64, 0, stream>>>(rowptr, col, dis, inv, B1h, 384, 0,
                                               B2h, 384, 0);
    k_gemm<0, 0, 0, 0><<<GB, 256, 0, stream>>>(B2h + 0, 384, wq2, bq2, nullptr,
                                               nullptr, 0, nullptr, 0,
                                               B1h + 0, 384, nullptr, 0, N_NODES);
    k_gemm<0, 0, 0, 0><<<GB, 256, 0, stream>>>(B2h + 128, 384, wx2, bx2, nullptr,
                                               nullptr, 0, nullptr, 0,
                                               B1h + 128, 384, nullptr, 0, N_NODES);
    k_gemm<0, 2, 0, 0><<<GB, 256, 0, stream>>>(B2h + 256, 384, wf2, bf2, nullptr,
                                               B1h + 0, 384, B1h + 128, 384,
                                               B1h + 256, 384, nullptr, 0, N_NODES);

    // mlp1
    k_gemm<1, 0, 0, 0><<<GB, 256, 0, stream>>>(B1h + 256, 384, m1w1, m1b1, nullptr,
                                               nullptr, 0, nullptr, 0,
                                               B2h + 0, 384, nullptr, 0, N_NODES);
    k_gemm<0, 0, 0, 1><<<GB, 256, 0, stream>>>(B2h + 0, 384, m1w2, m1b2, nullptr,
                                               nullptr, 0, nullptr, 0,
                                               xh, 128, xf, 128, N_NODES);

    // decode
    k_qemb<<<1, 128, 0, stream>>>(qp, xf, qe);
    k_node<<<N_NODES / 4, 256, 0, stream>>>(xf, qe, m2w1, m2b1, m2w2, m2b2, out, a, n2);
    k_loss<<<4096, 256, 0, stream>>>(ei, nei, xh, a, n2, qe, out + N_NODES);
}